// Round 2
// 1134.968 us; speedup vs baseline: 1.1017x; 1.1017x over previous
//
#include <hip/hip_runtime.h>

// ResidualVQ on MI355X (gfx950). ROUND 6: R5 pipeline + fence hardening.
// z: [65536,256] f32; codebooks: [4,1024,256] f32.
// Outputs (flat f32): z_q [65536*256], codes-as-float [65536*4], loss [1].
//
// R5 structure: global_load_lds DMA staging, CHUNK=32 double-buffer,
// counted vmcnt(8) + raw s_barrier (T3/T4), XOR-swizzled LDS via
// pre-swizzled global source (T2 / rule 21), shfl-butterfly top-2 merge,
// ballot-gated rescan. R6 adds: sched_barrier(0) after each raw s_barrier
// (rule 18: hipcc may hoist ds_read/DMA across inline-asm fences — the
// barrier alone is not a compiler memory fence), and s_setprio(1) around
// the MFMA cluster (T5; phase-split schedule is the regime where it pays).
// Screen numerics / rescan / epilogue identical to R4 (harness-verified).

#define NB 65536
#define ND 256
#define NK 1024
#define NL 4
#define MROWS 128
#define NBLK (NB / MROWS)      // 512
#define CHUNK 32               // codes per LDS chunk (double-buffered)
#define NCH (NK / CHUNK)       // 32
#define FLAG_MARGIN 1e-3f

typedef __attribute__((ext_vector_type(8))) short short8;
typedef __attribute__((ext_vector_type(4))) float f32x4;
typedef const __attribute__((address_space(1))) unsigned int gu32;
typedef __attribute__((address_space(3))) unsigned int lu32;

#define MFMA __builtin_amdgcn_mfma_f32_16x16x32_bf16

__device__ inline unsigned short f2bf(float x) {
  unsigned u = __float_as_uint(x);
  u = u + 0x7FFFu + ((u >> 16) & 1u);        // RNE to bf16 (inputs are finite)
  return (unsigned short)(u >> 16);
}
__device__ inline float bf2f(unsigned short h) {
  return __uint_as_float(((unsigned)h) << 16);
}

// ---- numpy-bit-exact fp32 kernels (R3-proven) ----
__device__ float np_sum256_sq(const float* __restrict__ a) {
#pragma clang fp contract(off)
  float out[2];
  for (int h = 0; h < 2; ++h) {
    const float* p = a + 128 * h;
    float r[8];
    for (int j = 0; j < 8; ++j) r[j] = p[j] * p[j];
    for (int i = 8; i < 128; i += 8)
      for (int j = 0; j < 8; ++j) r[j] += p[i + j] * p[i + j];
    out[h] = ((r[0] + r[1]) + (r[2] + r[3])) + ((r[4] + r[5]) + (r[6] + r[7]));
  }
  return out[0] + out[1];
}
__device__ float np_einsum256(const float* __restrict__ r,
                              const float* __restrict__ c) {
#pragma clang fp contract(off)
  float e[4] = {0.f, 0.f, 0.f, 0.f};
  for (int d = 0; d < 256; d += 4) {
    e[0] += r[d + 0] * c[d + 0];
    e[1] += r[d + 1] * c[d + 1];
    e[2] += r[d + 2] * c[d + 2];
    e[3] += r[d + 3] * c[d + 3];
  }
  return (e[0] + e[1]) + (e[2] + e[3]);
}
__device__ float np_dist(const float* __restrict__ resrow,
                         const float* __restrict__ crow, float r2) {
#pragma clang fp contract(off)
  float E = np_einsum256(resrow, crow);
  float c2 = np_sum256_sq(crow);
  float t1 = r2 - 2.0f * E;
  return t1 + c2;
}

// ---- prep: split codebook into bf16 hi/lo, compute c2 ----
__global__ void prep_split(const float* __restrict__ cb,
                           unsigned short* __restrict__ whi,
                           unsigned short* __restrict__ wlo) {
  int i = blockIdx.x * 256 + threadIdx.x;   // 4096 blocks cover 1,048,576
  float c = cb[i];
  unsigned short h = f2bf(c);
  whi[i] = h;
  wlo[i] = f2bf(c - bf2f(h));
}
__global__ void prep_c2(const float* __restrict__ cb, float* __restrict__ c2) {
  int k = blockIdx.x;                        // 4096 codes total
  int lane = threadIdx.x;                    // 64
  const float* p = cb + (size_t)k * ND + lane * 4;
  double s = (double)p[0]*p[0] + (double)p[1]*p[1]
           + (double)p[2]*p[2] + (double)p[3]*p[3];
  for (int off = 32; off >= 1; off >>= 1) s += __shfl_down(s, off);
  if (lane == 0) c2[k] = (float)s;
}

// LDS map (72192 B):
//  bufA: @0      32768  (hi rows 0..31 x 512B @0; lo @16384) XOR-swizzled
//  bufB: @32768  32768
//  c2s:  @65536  4096   float[1024]
//  selh: @69632  2048   int[128*4]
//  flags:@71680  512    int[128]
// overlays inside bufA (phase-disjoint, DMA drained, barrier-separated):
//  resr: @0      1024   rescan residual
//  redf: @1024   1024
//  redk: @2048   1024
//  lred: @0      2048   loss reduction (epilogue)

// DMA one 32-code chunk (hi+lo) into a 32KB buffer. 8 instrs/wave, 32 total.
// Linear LDS dest (wave-uniform base + lane*16); swizzle applied by
// pre-permuting the GLOBAL source column: slot scol holds gcol = scol^(row&7).
__device__ __forceinline__ void stage_chunk(
    const unsigned short* __restrict__ whi,
    const unsigned short* __restrict__ wlo,
    unsigned short* buf, int lvl, int ch, int wave, int lane) {
  const int rp = lane >> 5;          // row within the instr's row-pair
  const int scol = lane & 31;        // 16B slot within row
#pragma unroll
  for (int j = 0; j < 8; ++j) {
    const int g = wave * 8 + j;      // 0..31 instr id
    const int region = g >> 4;       // 0 = hi, 1 = lo
    const int gi = g & 15;           // row-pair index
    const int row = gi * 2 + rp;     // 0..31 code row in chunk
    const int gcol = scol ^ (row & 7);
    const unsigned short* src = (region ? wlo : whi)
        + (size_t)lvl * NK * ND + (size_t)(ch * CHUNK + row) * ND + gcol * 8;
    char* dst = (char*)buf + region * 16384 + gi * 1024;   // wave-uniform
    __builtin_amdgcn_global_load_lds((gu32*)src, (lu32*)dst, 16, 0, 0);
  }
}

__global__ __launch_bounds__(256, 2)
void rvq_main(const float* __restrict__ z, const float* __restrict__ cbf,
              const unsigned short* __restrict__ whi,
              const unsigned short* __restrict__ wlo,
              const float* __restrict__ c2w, float* __restrict__ out) {
  extern __shared__ char smem[];
  unsigned short* bufA = (unsigned short*)smem;
  unsigned short* bufB = (unsigned short*)(smem + 32768);
  float* c2s  = (float*)(smem + 65536);
  int*   selh = (int*)(smem + 69632);
  int*   flags= (int*)(smem + 71680);
  float* resr = (float*)smem;
  float* redf = (float*)(smem + 1024);
  int*   redk = (int*)(smem + 2048);
  double* lred= (double*)smem;

  const int tid  = threadIdx.x;
  const int wave = tid >> 6, lane = tid & 63;
  const int quad = lane >> 4, lx = lane & 15;
  const int blk  = blockIdx.x;

  for (int lvl = 0; lvl < NL; ++lvl) {
    __syncthreads();   // selh stable from prev level; overlays free
    // ---- stage c2 for this level ----
#pragma unroll
    for (int t = 0; t < 4; ++t)
      c2s[t * 256 + tid] = c2w[lvl * NK + t * 256 + tid];

    // ---- build A-fragments (register-resident, 32 rows/wave) ----
    short8 Ah[2][8], Al[2][8];
#pragma unroll
    for (int s = 0; s < 2; ++s) {
      const int rloc = wave * 32 + s * 16 + lx;
      const size_t rg = (size_t)(blk * MROWS + rloc);
#pragma unroll
      for (int ks = 0; ks < 8; ++ks) {
        const int k0 = 32 * ks + quad * 8;
        const float* zp = z + rg * ND + k0;
        float4 p0 = *(const float4*)zp;
        float4 p1 = *(const float4*)(zp + 4);
        for (int l = 0; l < lvl; ++l) {
          int sel = selh[rloc * 4 + l];
          const float* cp = cbf + (size_t)(l * NK + sel) * ND + k0;
          float4 q0 = *(const float4*)cp, q1 = *(const float4*)(cp + 4);
          p0.x -= q0.x; p0.y -= q0.y; p0.z -= q0.z; p0.w -= q0.w;
          p1.x -= q1.x; p1.y -= q1.y; p1.z -= q1.z; p1.w -= q1.w;
        }
        float v0[8] = {p0.x, p0.y, p0.z, p0.w, p1.x, p1.y, p1.z, p1.w};
#pragma unroll
        for (int j = 0; j < 8; ++j) {
          unsigned short h = f2bf(v0[j]);
          Ah[s][ks][j] = (short)h;
          Al[s][ks][j] = (short)f2bf(v0[j] - bf2f(h));
        }
      }
    }

    // ---- screen: per-lane top-2 over 8 (stripe,reg) streams ----
    float m1[8], m2[8]; int i1[8];
#pragma unroll
    for (int t = 0; t < 8; ++t) { m1[t] = 1e30f; m2[t] = 1e30f; i1[t] = 0; }

    // c2s visible + overlays done before any DMA lands in the buffers.
    __syncthreads();
    stage_chunk(whi, wlo, bufA, lvl, 0, wave, lane);
    stage_chunk(whi, wlo, bufB, lvl, 1, wave, lane);

#pragma unroll 1
    for (int ch = 0; ch < NCH; ++ch) {
      // wait for chunk ch's 8 DMAs (keep next chunk's 8 in flight).
      // NB: any compiler-issued VMEM inside this loop is YOUNGER than
      // chunk ch's DMAs, so vmcnt(8) still fully drains chunk ch.
      if (ch + 1 < NCH) asm volatile("s_waitcnt vmcnt(8)" ::: "memory");
      else              asm volatile("s_waitcnt vmcnt(0)" ::: "memory");
      __builtin_amdgcn_s_barrier();          // raw: no vmcnt drain
      __builtin_amdgcn_sched_barrier(0);     // rule 18: pin ds_reads below
      const unsigned short* bh = (ch & 1) ? bufB : bufA;
#pragma unroll 1
      for (int tile = 0; tile < 2; ++tile) {
        f32x4 a0a = {0,0,0,0}, a0b = {0,0,0,0}, a1a = {0,0,0,0}, a1b = {0,0,0,0};
        const int crow = tile * 16 + lx;
        const unsigned short* bp = bh + crow * 256;   // 512B row stride
        const int xr = lx & 7;                        // crow & 7
        __builtin_amdgcn_s_setprio(1);                // T5: favor MFMA wave
#pragma unroll
        for (int ks = 0; ks < 8; ks += 2) {
          const int s0 = ((ks * 4 + quad) ^ xr) * 8;      // swizzled slot, hi
          const int s1 = ((ks * 4 + 4 + quad) ^ xr) * 8;  // odd ks
          short8 vb0 = *(const short8*)(bp + s0);
          short8 wb0 = *(const short8*)(bp + 8192 + s0);  // lo region +16KB
          short8 vb1 = *(const short8*)(bp + s1);
          short8 wb1 = *(const short8*)(bp + 8192 + s1);
          a0a = MFMA(Ah[0][ks], vb0, a0a, 0, 0, 0);
          a1a = MFMA(Ah[1][ks], vb0, a1a, 0, 0, 0);
          a0a = MFMA(Al[0][ks], vb0, a0a, 0, 0, 0);
          a1a = MFMA(Al[1][ks], vb0, a1a, 0, 0, 0);
          a0a = MFMA(Ah[0][ks], wb0, a0a, 0, 0, 0);
          a1a = MFMA(Ah[1][ks], wb0, a1a, 0, 0, 0);
          a0b = MFMA(Ah[0][ks + 1], vb1, a0b, 0, 0, 0);
          a1b = MFMA(Ah[1][ks + 1], vb1, a1b, 0, 0, 0);
          a0b = MFMA(Al[0][ks + 1], vb1, a0b, 0, 0, 0);
          a1b = MFMA(Al[1][ks + 1], vb1, a1b, 0, 0, 0);
          a0b = MFMA(Ah[0][ks + 1], wb1, a0b, 0, 0, 0);
          a1b = MFMA(Ah[1][ks + 1], wb1, a1b, 0, 0, 0);
        }
        __builtin_amdgcn_s_setprio(0);
        const int kidx = ch * CHUNK + crow;
        const float c2v = c2s[kidx];
#pragma unroll
        for (int s = 0; s < 2; ++s)
#pragma unroll
          for (int r = 0; r < 4; ++r) {
            float e = (s == 0) ? (a0a[r] + a0b[r]) : (a1a[r] + a1b[r]);
            float d = fmaf(-2.0f, e, c2v);
            int st = s * 4 + r;
            if (d < m1[st]) { m2[st] = m1[st]; m1[st] = d; i1[st] = kidx; }
            else if (d < m2[st]) m2[st] = d;
          }
      }
      // my LDS reads retired before anyone overwrites this buffer
      asm volatile("s_waitcnt lgkmcnt(0)" ::: "memory");
      __builtin_amdgcn_s_barrier();          // raw: all waves done reading
      __builtin_amdgcn_sched_barrier(0);     // pin prefetch DMAs below barrier
      if (ch + 2 < NCH)
        stage_chunk(whi, wlo, (ch & 1) ? bufB : bufA, lvl, ch + 2, wave, lane);
    }
    // loop exit: vmcnt==0 (last iter drained), buffers free for overlays

    // ---- cross-lane top-2 merge: butterfly over the 16-lane lx group ----
    int myflag = 0;
#pragma unroll
    for (int t = 0; t < 8; ++t) {
      float a1 = m1[t], a2 = m2[t]; int ai = i1[t];
#pragma unroll
      for (int off = 1; off < 16; off <<= 1) {
        float o1 = __shfl_xor(a1, off);
        float o2 = __shfl_xor(a2, off);
        int   oi = __shfl_xor(ai, off);
        if (o1 < a1 || (o1 == a1 && oi < ai)) {
          a2 = fminf(a1, o2); a1 = o1; ai = oi;
        } else {
          a2 = fminf(a2, o1);
        }
      }
      if (lx == 0) {
        int rloc = wave * 32 + (t >> 2) * 16 + quad * 4 + (t & 3);
        selh[rloc * 4 + lvl] = ai;
        int f = (a2 - a1 <= FLAG_MARGIN) ? 1 : 0;
        flags[rloc] = f;
        myflag |= f;
      }
    }
    int anyf = __syncthreads_or(myflag);

    // ---- numpy-bit-exact full-K rescan of flagged rows (~0.1%) ----
    if (anyf) {
      for (int r = 0; r < MROWS; ++r) {
        if (flags[r]) {
          {
            float v = z[(size_t)(blk * MROWS + r) * ND + tid];
            for (int l = 0; l < lvl; ++l)
              v -= cbf[(size_t)(l * NK + selh[r * 4 + l]) * ND + tid];
            resr[tid] = v;
          }
          __syncthreads();
          float r2 = np_sum256_sq(resr);
          float bd = 1e30f; int bk = 0x7fffffff;
          for (int u = 0; u < 4; ++u) {
            int k = u * 256 + tid;
            float dd = np_dist(resr, cbf + (size_t)(lvl * NK + k) * ND, r2);
            if (dd < bd || (dd == bd && k < bk)) { bd = dd; bk = k; }
          }
          redf[tid] = bd; redk[tid] = bk;
          __syncthreads();
          if (tid == 0) {
            float gb = 1e30f; int gk = 0x7fffffff;
            for (int t2 = 0; t2 < 256; ++t2) {
              if (redf[t2] < gb || (redf[t2] == gb && redk[t2] < gk)) {
                gb = redf[t2]; gk = redk[t2];
              }
            }
            selh[r * 4 + lvl] = gk;
          }
          __syncthreads();
        }
      }
    }
  }

  // ---- epilogue: z_q = sum of selected codes (ref order), codes, loss ----
  __syncthreads();
  double lacc = 0.0;
#pragma unroll 1
  for (int it = 0; it < 32; ++it) {
    int i = it * 256 + tid;
    int row = i >> 6, dc = i & 63;
    size_t rg = (size_t)(blk * MROWS + row);
    float4 z4 = *(const float4*)(z + rg * ND + dc * 4);
    float4 q; q.x = 0.f; q.y = 0.f; q.z = 0.f; q.w = 0.f;
    for (int l = 0; l < NL; ++l) {
      int sel = selh[row * 4 + l];
      float4 c4 = *(const float4*)(cbf + (size_t)(l * NK + sel) * ND + dc * 4);
      q.x += c4.x; q.y += c4.y; q.z += c4.z; q.w += c4.w;
    }
    *(float4*)(out + rg * ND + dc * 4) = q;
    float dx = q.x - z4.x, dy = q.y - z4.y, dz = q.z - z4.z, dw = q.w - z4.w;
    lacc += (double)dx * dx + (double)dy * dy + (double)dz * dz + (double)dw * dw;
  }
  if (tid < MROWS) {
    for (int l = 0; l < NL; ++l)
      out[(size_t)NB * ND + (size_t)(blk * MROWS + tid) * NL + l] =
          (float)selh[tid * 4 + l];
  }
  __syncthreads();
  lred[tid] = lacc;
  __syncthreads();
  if (tid == 0) {
    double s = 0.0;
    for (int t = 0; t < 256; ++t) s += lred[t];
    atomicAdd(out + (size_t)NB * ND + (size_t)NB * NL,
              (float)(s / ((double)NB * (double)ND)));
  }
}

extern "C" void kernel_launch(void* const* d_in, const int* in_sizes, int n_in,
                              void* d_out, int out_size, void* d_ws, size_t ws_size,
                              hipStream_t stream) {
  const float* z  = (const float*)d_in[0];
  const float* cb = (const float*)d_in[1];
  float* out = (float*)d_out;

  unsigned short* whi = (unsigned short*)d_ws;                 // 2 MB
  unsigned short* wlo = whi + (size_t)NL * NK * ND;            // 2 MB
  float* c2w = (float*)(wlo + (size_t)NL * NK * ND);           // 16 KB

  // zero the loss slot (harness poisons d_out with 0xAA)
  hipMemsetAsync((void*)(out + (size_t)NB * ND + (size_t)NB * NL), 0,
                 sizeof(float), stream);

  prep_split<<<dim3(4096), dim3(256), 0, stream>>>(cb, whi, wlo);
  prep_c2<<<dim3(4096), dim3(64), 0, stream>>>(cb, c2w);

  const size_t shmem = 72192;
  hipFuncSetAttribute((const void*)rvq_main,
                      hipFuncAttributeMaxDynamicSharedMemorySize, (int)shmem);
  rvq_main<<<dim3(NBLK), dim3(256), shmem, stream>>>(z, cb, whi, wlo, c2w, out);
}